// Round 2
// baseline (256.101 us; speedup 1.0000x reference)
//
#include <hip/hip_runtime.h>

#define VOCAB 32000
#define DIM   128
#define BB    16
#define MM    4096
#define SS    4

#define PROJ_ROWS_PER_BLK 64     // 500 blocks
#define GEMV_NB  500             // blocks in gemv
#define GEMV_VC  (VOCAB / GEMV_NB)   // 64 v per block

// ---------------- init: u = enc_query ----------------
__global__ __launch_bounds__(256) void k_init(const float* __restrict__ q,
                                              float* __restrict__ u) {
    int i = blockIdx.x * 256 + threadIdx.x;   // grid covers exactly B*DIM
    u[i] = q[i];
}

// ---------------- proj: P[v][b] = dot(C[hop][v], u[b]) ----------------------
// block = 256 thr = 4 waves; wave handles 16 rows; lane: b = lane&15,
// rl = lane>>4 -> rows vb..vb+3. u staged in LDS (padded), C read broadcast.
__global__ __launch_bounds__(256) void k_proj(const float* __restrict__ C,
                                              const float* __restrict__ u,
                                              float* __restrict__ P,
                                              int hop) {
    __shared__ float4 us4[16][33];   // [b][k4], pad 32->33 granules
    int tid = threadIdx.x;
    {
        int i = tid;
        us4[i >> 5][i & 31] = ((const float4*)u)[i];
        i = tid + 256;
        us4[i >> 5][i & 31] = ((const float4*)u)[i];
    }
    __syncthreads();

    int wave = tid >> 6, lane = tid & 63;
    int b  = lane & 15;
    int rl = lane >> 4;
    int vb = blockIdx.x * PROJ_ROWS_PER_BLK + wave * 16 + rl * 4;

    const float4* C4 = (const float4*)(C + (size_t)hop * VOCAB * DIM);
    const float4* r0 = C4 + (size_t)(vb + 0) * 32;
    const float4* r1 = C4 + (size_t)(vb + 1) * 32;
    const float4* r2 = C4 + (size_t)(vb + 2) * 32;
    const float4* r3 = C4 + (size_t)(vb + 3) * 32;

    float a0 = 0.f, a1 = 0.f, a2 = 0.f, a3 = 0.f;
    #pragma unroll 4
    for (int k4 = 0; k4 < 32; ++k4) {
        float4 uu = us4[b][k4];
        float4 c0 = r0[k4], c1 = r1[k4], c2 = r2[k4], c3 = r3[k4];
        a0 += c0.x * uu.x + c0.y * uu.y + c0.z * uu.z + c0.w * uu.w;
        a1 += c1.x * uu.x + c1.y * uu.y + c1.z * uu.z + c1.w * uu.w;
        a2 += c2.x * uu.x + c2.y * uu.y + c2.z * uu.z + c2.w * uu.w;
        a3 += c3.x * uu.x + c3.y * uu.y + c3.z * uu.z + c3.w * uu.w;
    }
    P[(size_t)(vb + 0) * 16 + b] = a0;
    P[(size_t)(vb + 1) * 16 + b] = a1;
    P[(size_t)(vb + 2) * 16 + b] = a2;
    P[(size_t)(vb + 3) * 16 + b] = a3;
}

// ---------------- logits: lg[b,m] = sum_s P[st[s]][b] ------------------------
__global__ __launch_bounds__(256) void k_logits(const int* __restrict__ story,
                                                const float* __restrict__ P,
                                                float* __restrict__ lg) {
    int gid = blockIdx.x * 256 + threadIdx.x;   // b*MM + m, grid exact
    int b   = gid >> 12;
    int4 st = ((const int4*)story)[gid];
    lg[gid] = (P[(size_t)st.x * 16 + b] + P[(size_t)st.y * 16 + b]) +
              (P[(size_t)st.z * 16 + b] + P[(size_t)st.w * 16 + b]);
}

// ---------------- softmax stats: row max + sum of exp per batch --------------
__global__ __launch_bounds__(256) void k_stats(const float* __restrict__ lg,
                                               float* __restrict__ rmax,
                                               float* __restrict__ rsum) {
    int b = blockIdx.x;
    int t = threadIdx.x;
    const float* L = lg + (size_t)b * MM;

    float vals[MM / 256];
    float mx = -1e30f;
    #pragma unroll
    for (int i = 0; i < MM / 256; i++) {
        vals[i] = L[t + i * 256];
        mx = fmaxf(mx, vals[i]);
    }
    #pragma unroll
    for (int off = 32; off; off >>= 1) mx = fmaxf(mx, __shfl_down(mx, off, 64));

    __shared__ float sm[4];
    __shared__ float ss[4];
    int wave = t >> 6, lane = t & 63;
    if (lane == 0) sm[wave] = mx;
    __syncthreads();
    float bm = fmaxf(fmaxf(sm[0], sm[1]), fmaxf(sm[2], sm[3]));

    float sum = 0.f;
    #pragma unroll
    for (int i = 0; i < MM / 256; i++) sum += __expf(vals[i] - bm);
    #pragma unroll
    for (int off = 32; off; off >>= 1) sum += __shfl_down(sum, off, 64);
    if (lane == 0) ss[wave] = sum;
    __syncthreads();
    if (t == 0) {
        rmax[b] = bm;
        rsum[b] = ss[0] + ss[1] + ss[2] + ss[3];
    }
}

// ---------------- scatter: W[v][b] += prob[b,m] for each occurrence ----------
__global__ __launch_bounds__(256) void k_scatter(const int* __restrict__ story,
                                                 const float* __restrict__ lg,
                                                 const float* __restrict__ rmax,
                                                 const float* __restrict__ rsum,
                                                 float* __restrict__ W) {
    int gid = blockIdx.x * 256 + threadIdx.x;
    int b   = gid >> 12;
    float p = __expf(lg[gid] - rmax[b]) * (1.f / rsum[b]);
    int4 st = ((const int4*)story)[gid];
    atomicAdd(&W[(size_t)st.x * 16 + b], p);
    atomicAdd(&W[(size_t)st.y * 16 + b], p);
    atomicAdd(&W[(size_t)st.z * 16 + b], p);
    atomicAdd(&W[(size_t)st.w * 16 + b], p);
}

// ---------------- gemv: partial[nb][b][d] = sum_{v in chunk} W[v][b]*C[v][d] -
// block = 128 thr (d); W loads are block-uniform -> scalar-load broadcast
__global__ __launch_bounds__(128) void k_gemv(const float* __restrict__ C,
                                              const float* __restrict__ W,
                                              float* __restrict__ partial,
                                              int hop) {
    int nb = blockIdx.x;
    int d  = threadIdx.x;
    int v0 = nb * GEMV_VC;
    const float* Cn = C + (size_t)(hop + 1) * VOCAB * DIM;

    float acc[16];
    #pragma unroll
    for (int b = 0; b < 16; b++) acc[b] = 0.f;

    for (int vi = 0; vi < GEMV_VC; ++vi) {
        int v = v0 + vi;
        const float4* w4 = (const float4*)(W + (size_t)v * 16);
        float4 wa = w4[0], wb = w4[1], wc = w4[2], wd = w4[3];
        float c = Cn[(size_t)v * DIM + d];
        acc[0]  += wa.x * c;  acc[1]  += wa.y * c;
        acc[2]  += wa.z * c;  acc[3]  += wa.w * c;
        acc[4]  += wb.x * c;  acc[5]  += wb.y * c;
        acc[6]  += wb.z * c;  acc[7]  += wb.w * c;
        acc[8]  += wc.x * c;  acc[9]  += wc.y * c;
        acc[10] += wc.z * c;  acc[11] += wc.w * c;
        acc[12] += wd.x * c;  acc[13] += wd.y * c;
        acc[14] += wd.z * c;  acc[15] += wd.w * c;
    }
    #pragma unroll
    for (int b = 0; b < 16; b++)
        partial[((size_t)nb * 16 + b) * DIM + d] = acc[b];
}

// ---------------- update: u[b,d] += sum_nb partial[nb][b][d]; u1 at hop 0 ----
// 16 blocks x 512 thr: ch = t>>7 sums 1/4 of the nb range, LDS-combine
__global__ __launch_bounds__(512) void k_update(float* __restrict__ u,
                                                const float* __restrict__ partial,
                                                float* __restrict__ u1_out,
                                                int write_u1) {
    __shared__ float red[4][DIM];
    int b  = blockIdx.x;
    int t  = threadIdx.x;
    int d  = t & 127;
    int ch = t >> 7;                 // 0..3
    const int per = GEMV_NB / 4;     // 125

    float s = 0.f;
    for (int i = 0; i < per; ++i) {
        int nb = ch * per + i;
        s += partial[((size_t)nb * 16 + b) * DIM + d];
    }
    red[ch][d] = s;
    __syncthreads();
    if (ch == 0) {
        float tot = u[(size_t)b * DIM + d] +
                    ((red[0][d] + red[1][d]) + (red[2][d] + red[3][d]));
        u[(size_t)b * DIM + d] = tot;
        if (write_u1) u1_out[(size_t)b * DIM + d] = tot;
    }
}

extern "C" void kernel_launch(void* const* d_in, const int* in_sizes, int n_in,
                              void* d_out, int out_size, void* d_ws, size_t ws_size,
                              hipStream_t stream) {
    const int*   story = (const int*)d_in[0];
    const float* q     = (const float*)d_in[1];
    const float* C     = (const float*)d_in[2];

    float* out = (float*)d_out;           // [B*M logits][B*D u1]
    float* ws  = (float*)d_ws;

    // ws layout (floats), all 16B-aligned offsets
    float* u       = ws;                                  // 2048
    float* lg      = ws + 2048;                           // 65536
    float* rmax    = ws + 2048 + 65536;                   // 16
    float* rsum    = rmax + BB;                           // 16
    float* P       = rsum + BB;                           // VOCAB*16 = 512000
    float* W       = P + (size_t)VOCAB * 16;              // VOCAB*16 = 512000
    float* partial = W + (size_t)VOCAB * 16;              // GEMV_NB*16*128
    // total ~ 8.5 MB << ws

    float* out_u1 = out + BB * MM;

    k_init<<<(BB * DIM) / 256, 256, 0, stream>>>(q, u);

    for (int hop = 0; hop < 3; hop++) {
        float* lgp = (hop == 2) ? out : lg;
        k_proj<<<VOCAB / PROJ_ROWS_PER_BLK, 256, 0, stream>>>(C, u, P, hop);
        k_logits<<<(BB * MM) / 256, 256, 0, stream>>>(story, P, lgp);
        k_stats<<<BB, 256, 0, stream>>>(lgp, rmax, rsum);
        hipMemsetAsync(W, 0, (size_t)VOCAB * 16 * sizeof(float), stream);
        k_scatter<<<(BB * MM) / 256, 256, 0, stream>>>(story, lgp, rmax, rsum, W);
        k_gemv<<<GEMV_NB, 128, 0, stream>>>(C, W, partial, hop);
        k_update<<<BB, 512, 0, stream>>>(u, partial, out_u1, hop == 0 ? 1 : 0);
    }
}